// Round 5
// baseline (28223.239 us; speedup 1.0000x reference)
//
#include <hip/hip_runtime.h>
#include <hip/hip_bf16.h>

#define BB 256   // batch
#define TT 1024  // seq len
#define FF 64    // features
#define EE 256   // hidden

typedef _Float16 f16x8 __attribute__((ext_vector_type(8)));
typedef float    f32x4 __attribute__((ext_vector_type(4)));
typedef union { unsigned long long u[2]; f16x8 v; } U16;

#define MFMA(a,b,c) __builtin_amdgcn_mfma_f32_16x16x32_f16((a),(b),(c),0,0,0)

__device__ __forceinline__ float fsig(float v) {
    return __builtin_amdgcn_rcpf(1.f + __builtin_amdgcn_exp2f(v * -1.44269504089f));
}
__device__ __forceinline__ float ftanhf(float v) {
    return 1.f - 2.f * __builtin_amdgcn_rcpf(1.f + __builtin_amdgcn_exp2f(v * 2.88539008178f));
}
__device__ __forceinline__ f16x8 cvt2(f32x4 a, f32x4 b) {
    f16x8 r;
#pragma unroll
    for (int e = 0; e < 4; ++e) { r[e] = (_Float16)a[e]; r[4+e] = (_Float16)b[e]; }
    return r;
}

// ===========================================================================
// setup_all: permute weights into MFMA-fragment order (fp16), fuse decoder,
// zero the exchange flags. Fragment layout frag[(g*16+ct)*8+ks][lane][8]:
//   value = W[j][k], j = g*256+ct*16+(lane&15), k = ks*32+(lane>>4)*8+e
// grid 1217 x 64 threads.
// ===========================================================================
__global__ void setup_all(const float* __restrict__ eWih, const float* __restrict__ eWhh,
                          const float* __restrict__ ebih, const float* __restrict__ ebhh,
                          const float* __restrict__ dWih, const float* __restrict__ dWhh,
                          const float* __restrict__ dbih, const float* __restrict__ dbhh,
                          const float* __restrict__ Wd,   const float* __restrict__ bd,
                          _Float16* __restrict__ W16E, _Float16* __restrict__ W16D,
                          _Float16* __restrict__ wihP, _Float16* __restrict__ wdP,
                          float* __restrict__ biasEP, float* __restrict__ biasDP,
                          int* __restrict__ flags)
{
    const int blk = blockIdx.x, l = threadIdx.x, p = l & 15, q = l >> 4;
    if (blk < 512) {                        // encoder Whh permute
        const int g = blk >> 7, ct = (blk >> 3) & 15, ks = blk & 7;
        const int j = g*256 + ct*16 + p, kb = ks*32 + q*8;
        _Float16* o = W16E + ((size_t)blk*64 + l)*8;
#pragma unroll
        for (int e = 0; e < 8; ++e) o[e] = (_Float16)eWhh[j*EE + kb + e];
    } else if (blk < 1024) {                // decoder fused W' = dWhh + dWih@Wd
        const int b2 = blk - 512;
        const int g = b2 >> 7, ct = (b2 >> 3) & 15, ks = b2 & 7;
        const int j = g*256 + ct*16 + p, kb = ks*32 + q*8;
        _Float16* o = W16D + ((size_t)b2*64 + l)*8;
#pragma unroll
        for (int e = 0; e < 8; ++e) {
            const int k = kb + e;
            float acc = dWhh[j*EE + k];
            for (int f = 0; f < FF; ++f) acc += dWih[j*FF + f] * Wd[f*EE + k];
            o[e] = (_Float16)acc;
        }
    } else if (blk < 1152) {                // encoder Wih permute (K=64: 2 k-slices)
        const int b2 = blk - 1024;
        const int g = b2 >> 5, ct = (b2 >> 1) & 15, k2 = b2 & 1;
        const int j = g*256 + ct*16 + p, kb = k2*32 + q*8;
        _Float16* o = wihP + ((size_t)b2*64 + l)*8;
#pragma unroll
        for (int e = 0; e < 8; ++e) o[e] = (_Float16)eWih[j*FF + kb + e];
    } else if (blk < 1184) {                // Wd permute for out-proj
        const int b2 = blk - 1152;
        const int n = b2 >> 3, ks = b2 & 7;
        const int f = n*16 + p, kb = ks*32 + q*8;
        _Float16* o = wdP + ((size_t)b2*64 + l)*8;
#pragma unroll
        for (int e = 0; e < 8; ++e) o[e] = (_Float16)Wd[f*EE + kb + e];
    } else if (blk < 1216) {                // biases
        const int t2 = (blk - 1184)*64 + l;
        if (t2 < 1024) {
            biasEP[t2] = ebih[t2] + ebhh[t2];
        } else {
            const int j = t2 - 1024;
            float s = dbih[j] + dbhh[j];
            for (int f = 0; f < FF; ++f) s += dWih[j*FF + f] * bd[f];
            biasDP[j] = s;
        }
    } else {                                // zero exchange flags [16][2][16] ints
#pragma unroll
        for (int i = 0; i < 8; ++i) flags[l*8 + i] = 0;
    }
}

// ===========================================================================
// lstm_split: 32 blocks x 512 threads (8 waves, 2/SIMD -> 256-VGPR cap).
// Block (bg = blk&15, s = blk>>4) owns batch rows [16bg,16bg+16) and hidden
// half e in [128s, 128s+128) for ALL FOUR gates. Wave w owns col-tile
// ctg = 8s + w (16 e-cols x 4 gates) -> 32 weight frags = 128 VGPRs:
// the ENTIRE weight slice is register-resident. No LDS weights, no spills.
// Per step: own-half h from LDS (4 ds_read_b128), partner half via relaxed
// AGENT-scope atomics (sc1, coherent across XCDs without cache flushes),
// flag handshake with monotonic step counter (zeroed each launch).
// Encoder streams Wih frags from L2 (anti-LICM) + x loaded per step.
// Decoder h -> global Hbuf; out_proj does the dense projection in parallel.
// ===========================================================================
__global__ __launch_bounds__(512, 2) void lstm_split(
    const float* __restrict__ x,
    const _Float16* __restrict__ W16E,
    const _Float16* __restrict__ W16D,
    const _Float16* __restrict__ wihP,
    const float* __restrict__ biasEP,
    const float* __restrict__ biasDP,
    unsigned long long* __restrict__ Hx,   // [2][16][2][512] u64 frag-order
    int* __restrict__ flags,               // [16][2][16]
    _Float16* __restrict__ Hbuf)           // [1024][256][256] fp16
{
    __shared__ _Float16 hbS[2][16*128];    // own-half h, XOR-swizzled, dbuf

    const int tid = threadIdx.x;
    const int w = tid >> 6, lane = tid & 63;
    const int p = lane & 15, q = lane >> 4;
    const int bg = blockIdx.x & 15, s = blockIdx.x >> 4;
    const int b0 = bg << 4;
    const int ctg = s*8 + w;               // global col-tile 0..15
    const int ob = s*4, pb = 4 - s*4;      // own / partner global ks base

    int* pfl = flags + (bg*2 + (1 - s))*16;
    int* mfl = flags + (bg*2 + s)*16;
    unsigned long long* HxM0 = Hx + (((size_t)(0*16 + bg)*2 + s)*512);
    unsigned long long* HxM1 = Hx + (((size_t)(1*16 + bg)*2 + s)*512);
    unsigned long long* HxP0 = Hx + (((size_t)(0*16 + bg)*2 + (1 - s))*512);
    unsigned long long* HxP1 = Hx + (((size_t)(1*16 + bg)*2 + (1 - s))*512);

    // ---- all-gate register-resident weights (encoder first) ----
    f16x8 wv[4][8];
    {
        const f16x8* WF = (const f16x8*)W16E;
#pragma unroll
        for (int g = 0; g < 4; ++g)
#pragma unroll
            for (int ks = 0; ks < 8; ++ks)
                wv[g][ks] = WF[((g*16 + ctg)*8 + ks)*64 + lane];
    }
    float bs[4];
#pragma unroll
    for (int g = 0; g < 4; ++g) bs[g] = biasEP[g*256 + s*128 + w*16 + p];
    float cst[4] = {0.f, 0.f, 0.f, 0.f};

    const float* xrowp = x + (size_t)(b0 + p) * (TT*FF);

#define STEP(kk, ENC)                                                          \
{                                                                              \
    const int k_ = (kk);                                                       \
    f32x4 v0, v1, v2, v3;                                                      \
    if (ENC) {                                                                 \
        const float* xc = xrowp + (size_t)k_ * FF;                             \
        v0 = *(const f32x4*)(xc + q*8);      v1 = *(const f32x4*)(xc + q*8+4); \
        v2 = *(const f32x4*)(xc + 32 + q*8); v3 = *(const f32x4*)(xc + 32 + q*8 + 4); \
    }                                                                          \
    if (k_ > 0) {                                                              \
        if (tid == 0) {                                                        \
            int it_ = 0;                                                       \
            while (__hip_atomic_load(pfl, __ATOMIC_RELAXED,                    \
                       __HIP_MEMORY_SCOPE_AGENT) < k_ && it_ < (1 << 14)) ++it_;\
        }                                                                      \
        __syncthreads();                                                       \
        asm volatile("" ::: "memory");                                         \
    }                                                                          \
    f16x8 ha[8];                                                               \
    { f16x8 z_ = {}; _Pragma("unroll") for (int i2 = 0; i2 < 8; ++i2) ha[i2] = z_; } \
    if (k_ > 0) {                                                              \
        const _Float16* hbR = hbS[k_ & 1];                                     \
        _Pragma("unroll") for (int kl = 0; kl < 4; ++kl)                       \
            ha[ob + kl] = *(const f16x8*)(hbR + p*128 + (((kl*4 + q) ^ (p & 7))*8)); \
        unsigned long long* HP = (k_ & 1) ? HxP1 : HxP0;                       \
        _Pragma("unroll") for (int kl = 0; kl < 4; ++kl) {                     \
            U16 uu;                                                            \
            uu.u[0] = __hip_atomic_load(HP + (kl*64 + lane)*2 + 0,             \
                          __ATOMIC_RELAXED, __HIP_MEMORY_SCOPE_AGENT);         \
            uu.u[1] = __hip_atomic_load(HP + (kl*64 + lane)*2 + 1,             \
                          __ATOMIC_RELAXED, __HIP_MEMORY_SCOPE_AGENT);         \
            ha[pb + kl] = uu.v;                                                \
        }                                                                      \
    }                                                                          \
    f32x4 a0 = {0.f,0.f,0.f,0.f}, a1 = a0, a2 = a0, a3 = a0;                   \
    _Pragma("unroll") for (int kl = 0; kl < 4; ++kl) {                         \
        f16x8 hk = ha[ob + kl];                                                \
        a0 = MFMA(hk, wv[0][ob+kl], a0); a1 = MFMA(hk, wv[1][ob+kl], a1);      \
        a2 = MFMA(hk, wv[2][ob+kl], a2); a3 = MFMA(hk, wv[3][ob+kl], a3);      \
    }                                                                          \
    _Pragma("unroll") for (int kl = 0; kl < 4; ++kl) {                         \
        f16x8 hk = ha[pb + kl];                                                \
        a0 = MFMA(hk, wv[0][pb+kl], a0); a1 = MFMA(hk, wv[1][pb+kl], a1);      \
        a2 = MFMA(hk, wv[2][pb+kl], a2); a3 = MFMA(hk, wv[3][pb+kl], a3);      \
    }                                                                          \
    if (ENC) {                                                                 \
        const f16x8* WIHl = (const f16x8*)wihP;                                \
        asm volatile("" : "+v"(WIHl));                                         \
        f16x8 u0 = WIHl[((0*16 + ctg)*2 + 0)*64 + lane];                       \
        f16x8 u1 = WIHl[((0*16 + ctg)*2 + 1)*64 + lane];                       \
        f16x8 u2 = WIHl[((1*16 + ctg)*2 + 0)*64 + lane];                       \
        f16x8 u3 = WIHl[((1*16 + ctg)*2 + 1)*64 + lane];                       \
        f16x8 u4 = WIHl[((2*16 + ctg)*2 + 0)*64 + lane];                       \
        f16x8 u5 = WIHl[((2*16 + ctg)*2 + 1)*64 + lane];                       \
        f16x8 u6 = WIHl[((3*16 + ctg)*2 + 0)*64 + lane];                       \
        f16x8 u7 = WIHl[((3*16 + ctg)*2 + 1)*64 + lane];                       \
        f16x8 xa0 = cvt2(v0, v1), xa1 = cvt2(v2, v3);                          \
        a0 = MFMA(xa0, u0, a0); a0 = MFMA(xa1, u1, a0);                        \
        a1 = MFMA(xa0, u2, a1); a1 = MFMA(xa1, u3, a1);                        \
        a2 = MFMA(xa0, u4, a2); a2 = MFMA(xa1, u5, a2);                        \
        a3 = MFMA(xa0, u6, a3); a3 = MFMA(xa1, u7, a3);                        \
    }                                                                          \
    _Float16* hbW = hbS[(k_ + 1) & 1];                                         \
    _Pragma("unroll") for (int r = 0; r < 4; ++r) {                            \
        float I_ = fsig(a0[r] + bs[0]);                                        \
        float F_ = fsig(a1[r] + bs[1]);                                        \
        float G_ = ftanhf(a2[r] + bs[2]);                                      \
        float O_ = fsig(a3[r] + bs[3]);                                        \
        float c_ = F_ * cst[r] + I_ * G_;                                      \
        cst[r] = c_;                                                           \
        float hv_ = O_ * ftanhf(c_);                                           \
        const int row_ = q*4 + r;                                              \
        const int cg8_ = w*2 + (p >> 3);                                       \
        hbW[row_*128 + ((cg8_ ^ (row_ & 7))*8) + (p & 7)] = (_Float16)hv_;     \
    }                                                                          \
    __syncthreads();                                                           \
    {                                                                          \
        const int ksl_ = tid >> 7, ln_ = (tid >> 1) & 63, h4_ = tid & 1;       \
        const int pw_ = ln_ & 15, qw_ = ln_ >> 4;                              \
        unsigned long long vv_ = *(const unsigned long long*)                  \
            (hbW + pw_*128 + (((ksl_*4 + qw_) ^ (pw_ & 7))*8) + h4_*4);        \
        unsigned long long* HM = ((k_ + 1) & 1) ? HxM1 : HxM0;                 \
        __hip_atomic_store(HM + (ksl_*64 + ln_)*2 + h4_, vv_,                  \
                           __ATOMIC_RELAXED, __HIP_MEMORY_SCOPE_AGENT);        \
        if (k_ >= 1023) {                                                      \
            const int row2_ = tid >> 5, cg4_ = tid & 31;                       \
            unsigned long long hv2_ = *(const unsigned long long*)             \
                (hbW + row2_*128 + (((cg4_ >> 1) ^ (row2_ & 7))*8) + (cg4_ & 1)*4); \
            *(unsigned long long*)(Hbuf + ((size_t)(k_ - 1023)*BB + b0 + row2_)*EE \
                                   + s*128 + cg4_*4) = hv2_;                   \
        }                                                                      \
    }                                                                          \
    asm volatile("s_waitcnt vmcnt(0)" ::: "memory");                           \
    __syncthreads();                                                           \
    if (tid == 0)                                                              \
        __hip_atomic_store(mfl, k_ + 1, __ATOMIC_RELAXED,                      \
                           __HIP_MEMORY_SCOPE_AGENT);                          \
}

    // ================= encoder: iterations 0..1023 =================
#pragma unroll 1
    for (int k = 0; k < 1024; ++k) STEP(k, 1)

    // ================= decoder transition: reload fused W' =================
    {
        const f16x8* WF = (const f16x8*)W16D;
#pragma unroll
        for (int g = 0; g < 4; ++g)
#pragma unroll
            for (int ks = 0; ks < 8; ++ks)
                wv[g][ks] = WF[((g*16 + ctg)*8 + ks)*64 + lane];
#pragma unroll
        for (int g = 0; g < 4; ++g) bs[g] = biasDP[g*256 + s*128 + w*16 + p];
    }

    // ================= decoder: iterations 1024..2046 =================
#pragma unroll 1
    for (int k = 1024; k < 2047; ++k) STEP(k, 0)

#undef STEP
}

// ===========================================================================
// out_proj: out[t][b][f] = Hbuf[t][b][:] @ Wd^T + bd.  Fully parallel.
// grid 16384 (t*16+bk) x 256 threads (4 waves, one 16-col n-tile each).
// ===========================================================================
__global__ __launch_bounds__(256) void out_proj(const _Float16* __restrict__ Hbuf,
                                                const _Float16* __restrict__ wdP,
                                                const float* __restrict__ bd,
                                                float* __restrict__ out)
{
    const int blk = blockIdx.x, t = blk >> 4, bk = blk & 15;
    const int tid = threadIdx.x, n = tid >> 6, lane = tid & 63;
    const int p = lane & 15, q = lane >> 4;
    const _Float16* hrow = Hbuf + ((size_t)t*BB + bk*16 + p)*EE;
    const f16x8* WDP = (const f16x8*)wdP;
    float b = bd[n*16 + p];
    f32x4 acc = {b, b, b, b};
#pragma unroll
    for (int ks = 0; ks < 8; ++ks) {
        f16x8 a = *(const f16x8*)(hrow + ks*32 + q*8);
        f16x8 wv = WDP[(n*8 + ks)*64 + lane];
        acc = MFMA(a, wv, acc);
    }
    float* ob = out + ((size_t)t*BB + bk*16)*FF + n*16 + p;
#pragma unroll
    for (int r = 0; r < 4; ++r) ob[(q*4 + r)*FF] = acc[r];
}

// ===========================================================================
// Fallback path (round-0 kernel, verified-passing, slow) if ws too small.
// ===========================================================================
__global__ void setup_fb(const float* __restrict__ eWih, const float* __restrict__ eWhh,
                         const float* __restrict__ ebih, const float* __restrict__ ebhh,
                         const float* __restrict__ dWih, const float* __restrict__ dWhh,
                         const float* __restrict__ dbih, const float* __restrict__ dbhh,
                         const float* __restrict__ Wd,   const float* __restrict__ bd,
                         _Float16* __restrict__ whh16, _Float16* __restrict__ wp16,
                         _Float16* __restrict__ wih16, _Float16* __restrict__ wd16,
                         float* __restrict__ biasE, float* __restrict__ biasD)
{
    const int j = blockIdx.x, e = threadIdx.x;
    __shared__ float lih[FF];
    if (e < FF) lih[e] = dWih[j*FF + e];
    __syncthreads();
    float acc = dWhh[j*EE + e];
    for (int f = 0; f < FF; ++f) acc += lih[f] * Wd[f*EE + e];
    wp16[j*EE + e]  = (_Float16)acc;
    whh16[j*EE + e] = (_Float16)eWhh[j*EE + e];
    if (e < FF) wih16[j*FF + e] = (_Float16)eWih[j*FF + e];
    if (j < FF) wd16[j*EE + e]  = (_Float16)Wd[j*EE + e];
    if (e == 0) {
        float s = dbih[j] + dbhh[j];
        for (int f = 0; f < FF; ++f) s += lih[f] * bd[f];
        biasD[j] = s; biasE[j] = ebih[j] + ebhh[j];
    }
}

__global__ __launch_bounds__(1024, 4) void lstm_fb(
    const float* __restrict__ x, const _Float16* __restrict__ whhG,
    const _Float16* __restrict__ wpG, const _Float16* __restrict__ wihG,
    const _Float16* __restrict__ wdG, const float* __restrict__ biasE,
    const float* __restrict__ biasD, const float* __restrict__ bdp,
    float* __restrict__ out)
{
    const int tid = threadIdx.x, w = tid >> 6, lane = tid & 63;
    const int p = lane & 15, q = lane >> 4, b0 = blockIdx.x << 4;
    __shared__ _Float16 hbuf[2][16*256];
    f16x8 wgt[4][8]; f16x8 wih[4][2]; float be[4], bp[4];
#pragma unroll
    for (int g = 0; g < 4; ++g) {
        const int j = g*256 + w*16 + p;
#pragma unroll
        for (int ks = 0; ks < 8; ++ks) wgt[g][ks] = *(const f16x8*)(whhG + j*EE + ks*32 + q*8);
        wih[g][0] = *(const f16x8*)(wihG + j*FF + q*8);
        wih[g][1] = *(const f16x8*)(wihG + j*FF + 32 + q*8);
        be[g] = biasE[j]; bp[g] = biasD[j];
    }
    f16x8 ha[8] = {}; f32x4 cst = {0.f,0.f,0.f,0.f};
    const float* xb = x + (size_t)(b0 + p)*TT*FF;
    f32x4 r0 = *(const f32x4*)(xb + q*8), r1 = *(const f32x4*)(xb + q*8 + 4);
    f32x4 r2 = *(const f32x4*)(xb + 32 + q*8), r3 = *(const f32x4*)(xb + 32 + q*8 + 4);
    for (int t = 0; t < TT; ++t) {
        f16x8 xa0 = cvt2(r0, r1), xa1 = cvt2(r2, r3);
        f32x4 a0 = {be[0],be[0],be[0],be[0]}, a1 = {be[1],be[1],be[1],be[1]};
        f32x4 a2 = {be[2],be[2],be[2],be[2]}, a3 = {be[3],be[3],be[3],be[3]};
#pragma unroll
        for (int ks = 0; ks < 8; ++ks) {
            a0 = MFMA(ha[ks], wgt[0][ks], a0); a1 = MFMA(ha[ks], wgt[1][ks], a1);
            a2 = MFMA(ha[ks], wgt[2][ks], a2); a3 = MFMA(ha[ks], wgt[3][ks], a3);
        }
        a0 = MFMA(xa0, wih[0][0], a0); a0 = MFMA(xa1, wih[0][1], a0);
        a1 = MFMA(xa0, wih[1][0], a1); a1 = MFMA(xa1, wih[1][1], a1);
        a2 = MFMA(xa0, wih[2][0], a2); a2 = MFMA(xa1, wih[2][1], a2);
        a3 = MFMA(xa0, wih[3][0], a3); a3 = MFMA(xa1, wih[3][1], a3);
        if (t + 1 < TT) {
            const float* xn = xb + (size_t)(t+1)*FF;
            r0 = *(const f32x4*)(xn + q*8); r1 = *(const f32x4*)(xn + q*8 + 4);
            r2 = *(const f32x4*)(xn + 32 + q*8); r3 = *(const f32x4*)(xn + 32 + q*8 + 4);
        }
#pragma unroll
        for (int r = 0; r < 4; ++r) {
            float ivv = fsig(a0[r]), fvv = fsig(a1[r]), gv = ftanhf(a2[r]), ov = fsig(a3[r]);
            float c = fvv*cst[r] + ivv*gv; cst[r] = c;
            float hv = ov*ftanhf(c);
            const int row = q*4 + r;
            hbuf[t&1][row*256 + ((w*16+p) ^ ((row&7)<<3))] = (_Float16)hv;
        }
        __syncthreads();
        {
            const _Float16* hbp = hbuf[t&1];
#pragma unroll
            for (int ks = 0; ks < 8; ++ks)
                ha[ks] = *(const f16x8*)(hbp + p*256 + ((ks*32 + q*8) ^ ((p&7)<<3)));
        }
    }
#pragma unroll
    for (int g = 0; g < 4; ++g) {
        const int j = g*256 + w*16 + p;
#pragma unroll
        for (int ks = 0; ks < 8; ++ks) wgt[g][ks] = *(const f16x8*)(wpG + j*EE + ks*32 + q*8);
    }
    f16x8 wd[8] = {}; float bdv = 0.f;
    if (w < 4) {
#pragma unroll
        for (int ks = 0; ks < 8; ++ks) wd[ks] = *(const f16x8*)(wdG + (w*16+p)*EE + ks*32 + q*8);
        bdv = bdp[w*16 + p];
    }
    for (int t = 0; t < TT; ++t) {
        if (w < 4) {
            f32x4 oa = {bdv,bdv,bdv,bdv};
#pragma unroll
            for (int ks = 0; ks < 8; ++ks) oa = MFMA(ha[ks], wd[ks], oa);
            float* ob = out + (size_t)t*(BB*FF) + (size_t)b0*FF + (w*16 + p);
#pragma unroll
            for (int r = 0; r < 4; ++r) ob[(q*4 + r)*FF] = oa[r];
        }
        if (t == TT-1) break;
        f32x4 a0 = {bp[0],bp[0],bp[0],bp[0]}, a1 = {bp[1],bp[1],bp[1],bp[1]};
        f32x4 a2 = {bp[2],bp[2],bp[2],bp[2]}, a3 = {bp[3],bp[3],bp[3],bp[3]};
#pragma unroll
        for (int ks = 0; ks < 8; ++ks) {
            a0 = MFMA(ha[ks], wgt[0][ks], a0); a1 = MFMA(ha[ks], wgt[1][ks], a1);
            a2 = MFMA(ha[ks], wgt[2][ks], a2); a3 = MFMA(ha[ks], wgt[3][ks], a3);
        }
#pragma unroll
        for (int r = 0; r < 4; ++r) {
            float ivv = fsig(a0[r]), fvv = fsig(a1[r]), gv = ftanhf(a2[r]), ov = fsig(a3[r]);
            float c = fvv*cst[r] + ivv*gv; cst[r] = c;
            float hv = ov*ftanhf(c);
            const int row = q*4 + r;
            hbuf[t&1][row*256 + ((w*16+p) ^ ((row&7)<<3))] = (_Float16)hv;
        }
        __syncthreads();
        {
            const _Float16* hbp = hbuf[t&1];
#pragma unroll
            for (int ks = 0; ks < 8; ++ks)
                ha[ks] = *(const f16x8*)(hbp + p*256 + ((ks*32 + q*8) ^ ((p&7)<<3)));
        }
    }
}

// ---------------------------------------------------------------------------
extern "C" void kernel_launch(void* const* d_in, const int* in_sizes, int n_in,
                              void* d_out, int out_size, void* d_ws, size_t ws_size,
                              hipStream_t stream) {
    const float* x    = (const float*)d_in[0];
    const float* eWih = (const float*)d_in[1];
    const float* eWhh = (const float*)d_in[2];
    const float* ebih = (const float*)d_in[3];
    const float* ebhh = (const float*)d_in[4];
    const float* dWih = (const float*)d_in[5];
    const float* dWhh = (const float*)d_in[6];
    const float* dbih = (const float*)d_in[7];
    const float* dbhh = (const float*)d_in[8];
    const float* Wd   = (const float*)d_in[9];
    const float* bd   = (const float*)d_in[10];

    const size_t NEED = 2097152ull + 134217728ull;   // tables+Hx+flags | Hbuf
    if (ws_size >= NEED) {
        char* ws = (char*)d_ws;
        _Float16* W16E  = (_Float16*)(ws + 0);        // 512 KB
        _Float16* W16D  = (_Float16*)(ws + 524288);   // 512 KB
        _Float16* wihP  = (_Float16*)(ws + 1048576);  // 128 KB
        _Float16* wdP   = (_Float16*)(ws + 1179648);  // 32 KB
        float*    biasEP = (float*)(ws + 1212416);    // 4 KB
        float*    biasDP = (float*)(ws + 1216512);    // 4 KB
        unsigned long long* Hx = (unsigned long long*)(ws + 1310720); // 256 KB
        int*      flags = (int*)(ws + 1572864);       // 2 KB
        _Float16* Hbuf  = (_Float16*)(ws + 2097152);  // 128 MB

        hipLaunchKernelGGL(setup_all, dim3(1217), dim3(64), 0, stream,
                           eWih, eWhh, ebih, ebhh, dWih, dWhh, dbih, dbhh, Wd, bd,
                           W16E, W16D, wihP, wdP, biasEP, biasDP, flags);

        hipLaunchKernelGGL(lstm_split, dim3(32), dim3(512), 0, stream,
                           x, W16E, W16D, wihP, biasEP, biasDP, Hx, flags, Hbuf);

        hipLaunchKernelGGL(out_proj, dim3(16384), dim3(256), 0, stream,
                           Hbuf, wdP, bd, (float*)d_out);
    } else {
        char* ws = (char*)d_ws;
        _Float16* whh16 = (_Float16*)(ws + 0);
        _Float16* wp16  = (_Float16*)(ws + 524288);
        _Float16* wih16 = (_Float16*)(ws + 1048576);
        _Float16* wd16  = (_Float16*)(ws + 1179648);
        float*    biasE = (float*)(ws + 1212416);
        float*    biasD = (float*)(ws + 1216512);
        hipLaunchKernelGGL(setup_fb, dim3(1024), dim3(256), 0, stream,
                           eWih, eWhh, ebih, ebhh, dWih, dWhh, dbih, dbhh, Wd, bd,
                           whh16, wp16, wih16, wd16, biasE, biasD);
        hipLaunchKernelGGL(lstm_fb, dim3(16), dim3(1024), 0, stream,
                           x, whh16, wp16, wih16, wd16, biasE, biasD, bd, (float*)d_out);
    }
}

// Round 6
// 6589.192 us; speedup vs baseline: 4.2833x; 4.2833x over previous
//
#include <hip/hip_runtime.h>
#include <hip/hip_bf16.h>

#define BB 256   // batch
#define TT 1024  // seq len
#define FF 64    // features
#define EE 256   // hidden

typedef _Float16 f16x8 __attribute__((ext_vector_type(8)));
typedef float    f32x4 __attribute__((ext_vector_type(4)));
typedef union { unsigned long long u[2]; f16x8 v; } U16;

#define MFMA(a,b,c) __builtin_amdgcn_mfma_f32_16x16x32_f16((a),(b),(c),0,0,0)

__device__ __forceinline__ float fsig(float v) {
    return __builtin_amdgcn_rcpf(1.f + __builtin_amdgcn_exp2f(v * -1.44269504089f));
}
__device__ __forceinline__ float ftanhf(float v) {
    return 1.f - 2.f * __builtin_amdgcn_rcpf(1.f + __builtin_amdgcn_exp2f(v * 2.88539008178f));
}
__device__ __forceinline__ f16x8 cvt2(f32x4 a, f32x4 b) {
    f16x8 r;
#pragma unroll
    for (int e = 0; e < 4; ++e) { r[e] = (_Float16)a[e]; r[4+e] = (_Float16)b[e]; }
    return r;
}

// ===========================================================================
// setup_all: permute weights into MFMA-fragment order (fp16), fuse decoder,
// zero the exchange flags. Fragment layout frag[(g*16+ct)*8+ks][lane][8]:
//   value = W[j][k], j = g*256+ct*16+(lane&15), k = ks*32+(lane>>4)*8+e
// grid 1217 x 64 threads.
// ===========================================================================
__global__ void setup_all(const float* __restrict__ eWih, const float* __restrict__ eWhh,
                          const float* __restrict__ ebih, const float* __restrict__ ebhh,
                          const float* __restrict__ dWih, const float* __restrict__ dWhh,
                          const float* __restrict__ dbih, const float* __restrict__ dbhh,
                          const float* __restrict__ Wd,   const float* __restrict__ bd,
                          _Float16* __restrict__ W16E, _Float16* __restrict__ W16D,
                          _Float16* __restrict__ wihP, _Float16* __restrict__ wdP,
                          float* __restrict__ biasEP, float* __restrict__ biasDP,
                          int* __restrict__ flags)
{
    const int blk = blockIdx.x, l = threadIdx.x, p = l & 15, q = l >> 4;
    if (blk < 512) {                        // encoder Whh permute
        const int g = blk >> 7, ct = (blk >> 3) & 15, ks = blk & 7;
        const int j = g*256 + ct*16 + p, kb = ks*32 + q*8;
        _Float16* o = W16E + ((size_t)blk*64 + l)*8;
#pragma unroll
        for (int e = 0; e < 8; ++e) o[e] = (_Float16)eWhh[j*EE + kb + e];
    } else if (blk < 1024) {                // decoder fused W' = dWhh + dWih@Wd
        const int b2 = blk - 512;
        const int g = b2 >> 7, ct = (b2 >> 3) & 15, ks = b2 & 7;
        const int j = g*256 + ct*16 + p, kb = ks*32 + q*8;
        _Float16* o = W16D + ((size_t)b2*64 + l)*8;
#pragma unroll
        for (int e = 0; e < 8; ++e) {
            const int k = kb + e;
            float acc = dWhh[j*EE + k];
            for (int f = 0; f < FF; ++f) acc += dWih[j*FF + f] * Wd[f*EE + k];
            o[e] = (_Float16)acc;
        }
    } else if (blk < 1152) {                // encoder Wih permute (K=64: 2 k-slices)
        const int b2 = blk - 1024;
        const int g = b2 >> 5, ct = (b2 >> 1) & 15, k2 = b2 & 1;
        const int j = g*256 + ct*16 + p, kb = k2*32 + q*8;
        _Float16* o = wihP + ((size_t)b2*64 + l)*8;
#pragma unroll
        for (int e = 0; e < 8; ++e) o[e] = (_Float16)eWih[j*FF + kb + e];
    } else if (blk < 1184) {                // Wd permute for out-proj
        const int b2 = blk - 1152;
        const int n = b2 >> 3, ks = b2 & 7;
        const int f = n*16 + p, kb = ks*32 + q*8;
        _Float16* o = wdP + ((size_t)b2*64 + l)*8;
#pragma unroll
        for (int e = 0; e < 8; ++e) o[e] = (_Float16)Wd[f*EE + kb + e];
    } else if (blk < 1216) {                // biases
        const int t2 = (blk - 1184)*64 + l;
        if (t2 < 1024) {
            biasEP[t2] = ebih[t2] + ebhh[t2];
        } else {
            const int j = t2 - 1024;
            float s = dbih[j] + dbhh[j];
            for (int f = 0; f < FF; ++f) s += dWih[j*FF + f] * bd[f];
            biasDP[j] = s;
        }
    } else {                                // zero exchange flags
#pragma unroll
        for (int i = 0; i < 8; ++i) flags[l*8 + i] = 0;
    }
}

// ===========================================================================
// lstm_split v2: 32 blocks x 512 threads (8 waves, 2/SIMD -> 256-VGPR cap).
// Block (bg = blk&15, s = blk>>4) owns batch rows [16bg,16bg+16) and hidden
// half e in [128s,128s+128) for ALL FOUR gates. Wave w owns col-tile
// ctg = 8s+w. Weights held as wvO[4][4] (own K-half) + wvP[4][4] (partner
// K-half) = 128 VGPRs -- ALL register indices compile-time (rule #20 fix;
// round-5's wv[g][ob+kl] runtime indexing demoted 160 regs to scratch:
// VGPR_Count=104, FETCH 175MB, 28ms). Runtime s only in ADDRESSES.
// Per step: own-half h via LDS ping-pong, partner half via relaxed
// agent-scope atomics + monotonic flag handshake (race-free: double buffer
// by step parity, flag k+1 set only after vmcnt(0) drain of data stores).
// Encoder streams Wih frags from L2 (anti-LICM) + x loads issued pre-poll.
// Decoder h -> global Hbuf; out_proj does the dense projection in parallel.
// ===========================================================================
__global__ __launch_bounds__(512, 2) void lstm_split(
    const float* __restrict__ x,
    const _Float16* __restrict__ W16E,
    const _Float16* __restrict__ W16D,
    const _Float16* __restrict__ wihP,
    const float* __restrict__ biasEP,
    const float* __restrict__ biasDP,
    unsigned long long* __restrict__ Hx,   // [2][16][2][512] u64 frag-order
    int* __restrict__ flags,               // [16][2][16]
    _Float16* __restrict__ Hbuf)           // [1024][256][256] fp16
{
    __shared__ _Float16 hbS[2][16*128];    // own-half h, XOR-swizzled, dbuf

    const int tid = threadIdx.x;
    const int w = tid >> 6, lane = tid & 63;
    const int p = lane & 15, q = lane >> 4;
    const int bg = blockIdx.x & 15, s = blockIdx.x >> 4;
    const int b0 = bg << 4;
    const int ctg = s*8 + w;               // global col-tile 0..15

    int* pfl = flags + (bg*2 + (1 - s))*16;
    int* mfl = flags + (bg*2 + s)*16;
    unsigned long long* HxM0 = Hx + (((size_t)(0*16 + bg)*2 + s)*512);
    unsigned long long* HxM1 = Hx + (((size_t)(1*16 + bg)*2 + s)*512);
    unsigned long long* HxP0 = Hx + (((size_t)(0*16 + bg)*2 + (1 - s))*512);
    unsigned long long* HxP1 = Hx + (((size_t)(1*16 + bg)*2 + (1 - s))*512);

    // ---- all-gate register-resident weights, split own/partner K-half ----
    // own K-half: global ks = s*4+kl ; partner: global ks = (1-s)*4+kl
    f16x8 wvO[4][4], wvP[4][4];
    {
        const f16x8* WF = (const f16x8*)W16E;
#pragma unroll
        for (int g = 0; g < 4; ++g)
#pragma unroll
            for (int kl = 0; kl < 4; ++kl) {
                wvO[g][kl] = WF[((g*16 + ctg)*8 + (s*4 + kl))*64 + lane];
                wvP[g][kl] = WF[((g*16 + ctg)*8 + ((1 - s)*4 + kl))*64 + lane];
            }
    }
    float bs[4];
#pragma unroll
    for (int g = 0; g < 4; ++g) bs[g] = biasEP[g*256 + s*128 + w*16 + p];
    float cst[4] = {0.f, 0.f, 0.f, 0.f};

    const float* xrowp = x + (size_t)(b0 + p) * (TT*FF);

#define STEP(kk, ENC)                                                          \
{                                                                              \
    const int k_ = (kk);                                                       \
    f16x8 xa0, xa1;                                                            \
    if (ENC) {  /* issue x loads before the poll (latency cover) */            \
        const float* xc = xrowp + (size_t)k_ * FF;                             \
        f32x4 v0 = *(const f32x4*)(xc + q*8);                                  \
        f32x4 v1 = *(const f32x4*)(xc + q*8 + 4);                              \
        f32x4 v2 = *(const f32x4*)(xc + 32 + q*8);                             \
        f32x4 v3 = *(const f32x4*)(xc + 32 + q*8 + 4);                         \
        xa0 = cvt2(v0, v1); xa1 = cvt2(v2, v3);                                \
    }                                                                          \
    if (k_ > 0) {                                                              \
        if (tid == 0) {                                                        \
            int it_ = 0;                                                       \
            while (__hip_atomic_load(pfl, __ATOMIC_RELAXED,                    \
                       __HIP_MEMORY_SCOPE_AGENT) < k_ && it_ < (1 << 14)) ++it_;\
        }                                                                      \
        __syncthreads();                                                       \
        asm volatile("" ::: "memory");                                         \
    }                                                                          \
    f16x8 hown[4], hpart[4];                                                   \
    if (k_ > 0) {                                                              \
        const _Float16* hbR = hbS[k_ & 1];                                     \
        _Pragma("unroll") for (int kl = 0; kl < 4; ++kl)                       \
            hown[kl] = *(const f16x8*)(hbR + p*128 + (((kl*4 + q) ^ (p & 7))*8)); \
        unsigned long long* HP = (k_ & 1) ? HxP1 : HxP0;                       \
        _Pragma("unroll") for (int kl = 0; kl < 4; ++kl) {                     \
            U16 uu;                                                            \
            uu.u[0] = __hip_atomic_load(HP + (kl*64 + lane)*2 + 0,             \
                          __ATOMIC_RELAXED, __HIP_MEMORY_SCOPE_AGENT);         \
            uu.u[1] = __hip_atomic_load(HP + (kl*64 + lane)*2 + 1,             \
                          __ATOMIC_RELAXED, __HIP_MEMORY_SCOPE_AGENT);         \
            hpart[kl] = uu.v;                                                  \
        }                                                                      \
    } else {                                                                   \
        f16x8 z_ = {};                                                         \
        _Pragma("unroll") for (int kl = 0; kl < 4; ++kl) { hown[kl] = z_; hpart[kl] = z_; } \
    }                                                                          \
    f32x4 a0 = {0.f,0.f,0.f,0.f}, a1 = a0, a2 = a0, a3 = a0;                   \
    _Pragma("unroll") for (int kl = 0; kl < 4; ++kl) {                         \
        a0 = MFMA(hown[kl], wvO[0][kl], a0); a1 = MFMA(hown[kl], wvO[1][kl], a1); \
        a2 = MFMA(hown[kl], wvO[2][kl], a2); a3 = MFMA(hown[kl], wvO[3][kl], a3); \
    }                                                                          \
    _Pragma("unroll") for (int kl = 0; kl < 4; ++kl) {                         \
        a0 = MFMA(hpart[kl], wvP[0][kl], a0); a1 = MFMA(hpart[kl], wvP[1][kl], a1); \
        a2 = MFMA(hpart[kl], wvP[2][kl], a2); a3 = MFMA(hpart[kl], wvP[3][kl], a3); \
    }                                                                          \
    if (ENC) {  /* streamed Wih frags, short live ranges */                    \
        const f16x8* WIHl = (const f16x8*)wihP;                                \
        asm volatile("" : "+v"(WIHl));                                         \
        { f16x8 u0 = WIHl[((0*16 + ctg)*2 + 0)*64 + lane];                     \
          f16x8 u1 = WIHl[((0*16 + ctg)*2 + 1)*64 + lane];                     \
          a0 = MFMA(xa0, u0, a0); a0 = MFMA(xa1, u1, a0); }                    \
        { f16x8 u0 = WIHl[((1*16 + ctg)*2 + 0)*64 + lane];                     \
          f16x8 u1 = WIHl[((1*16 + ctg)*2 + 1)*64 + lane];                     \
          a1 = MFMA(xa0, u0, a1); a1 = MFMA(xa1, u1, a1); }                    \
        { f16x8 u0 = WIHl[((2*16 + ctg)*2 + 0)*64 + lane];                     \
          f16x8 u1 = WIHl[((2*16 + ctg)*2 + 1)*64 + lane];                     \
          a2 = MFMA(xa0, u0, a2); a2 = MFMA(xa1, u1, a2); }                    \
        { f16x8 u0 = WIHl[((3*16 + ctg)*2 + 0)*64 + lane];                     \
          f16x8 u1 = WIHl[((3*16 + ctg)*2 + 1)*64 + lane];                     \
          a3 = MFMA(xa0, u0, a3); a3 = MFMA(xa1, u1, a3); }                    \
    }                                                                          \
    _Float16* hbW = hbS[(k_ + 1) & 1];                                         \
    _Pragma("unroll") for (int r = 0; r < 4; ++r) {                            \
        float I_ = fsig(a0[r] + bs[0]);                                        \
        float F_ = fsig(a1[r] + bs[1]);                                        \
        float G_ = ftanhf(a2[r] + bs[2]);                                      \
        float O_ = fsig(a3[r] + bs[3]);                                        \
        float c_ = F_ * cst[r] + I_ * G_;                                      \
        cst[r] = c_;                                                           \
        float hv_ = O_ * ftanhf(c_);                                           \
        const int row_ = q*4 + r;                                              \
        const int cg8_ = w*2 + (p >> 3);                                       \
        hbW[row_*128 + ((cg8_ ^ (row_ & 7))*8) + (p & 7)] = (_Float16)hv_;     \
    }                                                                          \
    __syncthreads();                                                           \
    {                                                                          \
        const int ksl_ = tid >> 7, ln_ = (tid >> 1) & 63, h4_ = tid & 1;       \
        const int pw_ = ln_ & 15, qw_ = ln_ >> 4;                              \
        unsigned long long vv_ = *(const unsigned long long*)                  \
            (hbW + pw_*128 + (((ksl_*4 + qw_) ^ (pw_ & 7))*8) + h4_*4);        \
        unsigned long long* HM = ((k_ + 1) & 1) ? HxM1 : HxM0;                 \
        __hip_atomic_store(HM + (ksl_*64 + ln_)*2 + h4_, vv_,                  \
                           __ATOMIC_RELAXED, __HIP_MEMORY_SCOPE_AGENT);        \
        if (k_ >= 1023) {                                                      \
            const int row2_ = tid >> 5, cg4_ = tid & 31;                       \
            unsigned long long hv2_ = *(const unsigned long long*)             \
                (hbW + row2_*128 + (((cg4_ >> 1) ^ (row2_ & 7))*8) + (cg4_ & 1)*4); \
            *(unsigned long long*)(Hbuf + ((size_t)(k_ - 1023)*BB + b0 + row2_)*EE \
                                   + s*128 + cg4_*4) = hv2_;                   \
        }                                                                      \
    }                                                                          \
    asm volatile("s_waitcnt vmcnt(0)" ::: "memory");                           \
    __syncthreads();                                                           \
    if (tid == 0)                                                              \
        __hip_atomic_store(mfl, k_ + 1, __ATOMIC_RELAXED,                      \
                           __HIP_MEMORY_SCOPE_AGENT);                          \
}

    // ================= encoder: iterations 0..1023 =================
#pragma unroll 1
    for (int k = 0; k < 1024; ++k) STEP(k, 1)

    // ================= decoder transition: reload fused W' =================
    {
        const f16x8* WF = (const f16x8*)W16D;
#pragma unroll
        for (int g = 0; g < 4; ++g)
#pragma unroll
            for (int kl = 0; kl < 4; ++kl) {
                wvO[g][kl] = WF[((g*16 + ctg)*8 + (s*4 + kl))*64 + lane];
                wvP[g][kl] = WF[((g*16 + ctg)*8 + ((1 - s)*4 + kl))*64 + lane];
            }
#pragma unroll
        for (int g = 0; g < 4; ++g) bs[g] = biasDP[g*256 + s*128 + w*16 + p];
    }

    // ================= decoder: iterations 1024..2046 =================
#pragma unroll 1
    for (int k = 1024; k < 2047; ++k) STEP(k, 0)

#undef STEP
}

// ===========================================================================
// out_proj: out[t][b][f] = Hbuf[t][b][:] @ Wd^T + bd.  Fully parallel.
// grid 16384 (t*16+bk) x 256 threads (4 waves, one 16-col n-tile each).
// ===========================================================================
__global__ __launch_bounds__(256) void out_proj(const _Float16* __restrict__ Hbuf,
                                                const _Float16* __restrict__ wdP,
                                                const float* __restrict__ bd,
                                                float* __restrict__ out)
{
    const int blk = blockIdx.x, t = blk >> 4, bk = blk & 15;
    const int tid = threadIdx.x, n = tid >> 6, lane = tid & 63;
    const int p = lane & 15, q = lane >> 4;
    const _Float16* hrow = Hbuf + ((size_t)t*BB + bk*16 + p)*EE;
    const f16x8* WDP = (const f16x8*)wdP;
    float b = bd[n*16 + p];
    f32x4 acc = {b, b, b, b};
#pragma unroll
    for (int ks = 0; ks < 8; ++ks) {
        f16x8 a = *(const f16x8*)(hrow + ks*32 + q*8);
        f16x8 wv = WDP[(n*8 + ks)*64 + lane];
        acc = MFMA(a, wv, acc);
    }
    float* ob = out + ((size_t)t*BB + bk*16)*FF + n*16 + p;
#pragma unroll
    for (int r = 0; r < 4; ++r) ob[(q*4 + r)*FF] = acc[r];
}

// ===========================================================================
// Fallback path (round-0 kernel, verified-passing, slow) if ws too small.
// ===========================================================================
__global__ void setup_fb(const float* __restrict__ eWih, const float* __restrict__ eWhh,
                         const float* __restrict__ ebih, const float* __restrict__ ebhh,
                         const float* __restrict__ dWih, const float* __restrict__ dWhh,
                         const float* __restrict__ dbih, const float* __restrict__ dbhh,
                         const float* __restrict__ Wd,   const float* __restrict__ bd,
                         _Float16* __restrict__ whh16, _Float16* __restrict__ wp16,
                         _Float16* __restrict__ wih16, _Float16* __restrict__ wd16,
                         float* __restrict__ biasE, float* __restrict__ biasD)
{
    const int j = blockIdx.x, e = threadIdx.x;
    __shared__ float lih[FF];
    if (e < FF) lih[e] = dWih[j*FF + e];
    __syncthreads();
    float acc = dWhh[j*EE + e];
    for (int f = 0; f < FF; ++f) acc += lih[f] * Wd[f*EE + e];
    wp16[j*EE + e]  = (_Float16)acc;
    whh16[j*EE + e] = (_Float16)eWhh[j*EE + e];
    if (e < FF) wih16[j*FF + e] = (_Float16)eWih[j*FF + e];
    if (j < FF) wd16[j*EE + e]  = (_Float16)Wd[j*EE + e];
    if (e == 0) {
        float s = dbih[j] + dbhh[j];
        for (int f = 0; f < FF; ++f) s += lih[f] * bd[f];
        biasD[j] = s; biasE[j] = ebih[j] + ebhh[j];
    }
}

__global__ __launch_bounds__(1024, 4) void lstm_fb(
    const float* __restrict__ x, const _Float16* __restrict__ whhG,
    const _Float16* __restrict__ wpG, const _Float16* __restrict__ wihG,
    const _Float16* __restrict__ wdG, const float* __restrict__ biasE,
    const float* __restrict__ biasD, const float* __restrict__ bdp,
    float* __restrict__ out)
{
    const int tid = threadIdx.x, w = tid >> 6, lane = tid & 63;
    const int p = lane & 15, q = lane >> 4, b0 = blockIdx.x << 4;
    __shared__ _Float16 hbuf[2][16*256];
    f16x8 wgt[4][8]; f16x8 wih[4][2]; float be[4], bp[4];
#pragma unroll
    for (int g = 0; g < 4; ++g) {
        const int j = g*256 + w*16 + p;
#pragma unroll
        for (int ks = 0; ks < 8; ++ks) wgt[g][ks] = *(const f16x8*)(whhG + j*EE + ks*32 + q*8);
        wih[g][0] = *(const f16x8*)(wihG + j*FF + q*8);
        wih[g][1] = *(const f16x8*)(wihG + j*FF + 32 + q*8);
        be[g] = biasE[j]; bp[g] = biasD[j];
    }
    f16x8 ha[8] = {}; f32x4 cst = {0.f,0.f,0.f,0.f};
    const float* xb = x + (size_t)(b0 + p)*TT*FF;
    f32x4 r0 = *(const f32x4*)(xb + q*8), r1 = *(const f32x4*)(xb + q*8 + 4);
    f32x4 r2 = *(const f32x4*)(xb + 32 + q*8), r3 = *(const f32x4*)(xb + 32 + q*8 + 4);
    for (int t = 0; t < TT; ++t) {
        f16x8 xa0 = cvt2(r0, r1), xa1 = cvt2(r2, r3);
        f32x4 a0 = {be[0],be[0],be[0],be[0]}, a1 = {be[1],be[1],be[1],be[1]};
        f32x4 a2 = {be[2],be[2],be[2],be[2]}, a3 = {be[3],be[3],be[3],be[3]};
#pragma unroll
        for (int ks = 0; ks < 8; ++ks) {
            a0 = MFMA(ha[ks], wgt[0][ks], a0); a1 = MFMA(ha[ks], wgt[1][ks], a1);
            a2 = MFMA(ha[ks], wgt[2][ks], a2); a3 = MFMA(ha[ks], wgt[3][ks], a3);
        }
        a0 = MFMA(xa0, wih[0][0], a0); a0 = MFMA(xa1, wih[0][1], a0);
        a1 = MFMA(xa0, wih[1][0], a1); a1 = MFMA(xa1, wih[1][1], a1);
        a2 = MFMA(xa0, wih[2][0], a2); a2 = MFMA(xa1, wih[2][1], a2);
        a3 = MFMA(xa0, wih[3][0], a3); a3 = MFMA(xa1, wih[3][1], a3);
        if (t + 1 < TT) {
            const float* xn = xb + (size_t)(t+1)*FF;
            r0 = *(const f32x4*)(xn + q*8); r1 = *(const f32x4*)(xn + q*8 + 4);
            r2 = *(const f32x4*)(xn + 32 + q*8); r3 = *(const f32x4*)(xn + 32 + q*8 + 4);
        }
#pragma unroll
        for (int r = 0; r < 4; ++r) {
            float ivv = fsig(a0[r]), fvv = fsig(a1[r]), gv = ftanhf(a2[r]), ov = fsig(a3[r]);
            float c = fvv*cst[r] + ivv*gv; cst[r] = c;
            float hv = ov*ftanhf(c);
            const int row = q*4 + r;
            hbuf[t&1][row*256 + ((w*16+p) ^ ((row&7)<<3))] = (_Float16)hv;
        }
        __syncthreads();
        {
            const _Float16* hbp = hbuf[t&1];
#pragma unroll
            for (int ks = 0; ks < 8; ++ks)
                ha[ks] = *(const f16x8*)(hbp + p*256 + ((ks*32 + q*8) ^ ((p&7)<<3)));
        }
    }
#pragma unroll
    for (int g = 0; g < 4; ++g) {
        const int j = g*256 + w*16 + p;
#pragma unroll
        for (int ks = 0; ks < 8; ++ks) wgt[g][ks] = *(const f16x8*)(wpG + j*EE + ks*32 + q*8);
    }
    f16x8 wd[8] = {}; float bdv = 0.f;
    if (w < 4) {
#pragma unroll
        for (int ks = 0; ks < 8; ++ks) wd[ks] = *(const f16x8*)(wdG + (w*16+p)*EE + ks*32 + q*8);
        bdv = bdp[w*16 + p];
    }
    for (int t = 0; t < TT; ++t) {
        if (w < 4) {
            f32x4 oa = {bdv,bdv,bdv,bdv};
#pragma unroll
            for (int ks = 0; ks < 8; ++ks) oa = MFMA(ha[ks], wd[ks], oa);
            float* ob = out + (size_t)t*(BB*FF) + (size_t)b0*FF + (w*16 + p);
#pragma unroll
            for (int r = 0; r < 4; ++r) ob[(q*4 + r)*FF] = oa[r];
        }
        if (t == TT-1) break;
        f32x4 a0 = {bp[0],bp[0],bp[0],bp[0]}, a1 = {bp[1],bp[1],bp[1],bp[1]};
        f32x4 a2 = {bp[2],bp[2],bp[2],bp[2]}, a3 = {bp[3],bp[3],bp[3],bp[3]};
#pragma unroll
        for (int ks = 0; ks < 8; ++ks) {
            a0 = MFMA(ha[ks], wgt[0][ks], a0); a1 = MFMA(ha[ks], wgt[1][ks], a1);
            a2 = MFMA(ha[ks], wgt[2][ks], a2); a3 = MFMA(ha[ks], wgt[3][ks], a3);
        }
#pragma unroll
        for (int r = 0; r < 4; ++r) {
            float ivv = fsig(a0[r]), fvv = fsig(a1[r]), gv = ftanhf(a2[r]), ov = fsig(a3[r]);
            float c = fvv*cst[r] + ivv*gv; cst[r] = c;
            float hv = ov*ftanhf(c);
            const int row = q*4 + r;
            hbuf[t&1][row*256 + ((w*16+p) ^ ((row&7)<<3))] = (_Float16)hv;
        }
        __syncthreads();
        {
            const _Float16* hbp = hbuf[t&1];
#pragma unroll
            for (int ks = 0; ks < 8; ++ks)
                ha[ks] = *(const f16x8*)(hbp + p*256 + ((ks*32 + q*8) ^ ((p&7)<<3)));
        }
    }
}

// ---------------------------------------------------------------------------
extern "C" void kernel_launch(void* const* d_in, const int* in_sizes, int n_in,
                              void* d_out, int out_size, void* d_ws, size_t ws_size,
                              hipStream_t stream) {
    const float* x    = (const float*)d_in[0];
    const float* eWih = (const float*)d_in[1];
    const float* eWhh = (const float*)d_in[2];
    const float* ebih = (const float*)d_in[3];
    const float* ebhh = (const float*)d_in[4];
    const float* dWih = (const float*)d_in[5];
    const float* dWhh = (const float*)d_in[6];
    const float* dbih = (const float*)d_in[7];
    const float* dbhh = (const float*)d_in[8];
    const float* Wd   = (const float*)d_in[9];
    const float* bd   = (const float*)d_in[10];

    const size_t NEED = 2097152ull + 134217728ull;   // tables+Hx+flags | Hbuf
    if (ws_size >= NEED) {
        char* ws = (char*)d_ws;
        _Float16* W16E  = (_Float16*)(ws + 0);        // 512 KB
        _Float16* W16D  = (_Float16*)(ws + 524288);   // 512 KB
        _Float16* wihP  = (_Float16*)(ws + 1048576);  // 128 KB
        _Float16* wdP   = (_Float16*)(ws + 1179648);  // 32 KB
        float*    biasEP = (float*)(ws + 1212416);    // 4 KB
        float*    biasDP = (float*)(ws + 1216512);    // 4 KB
        unsigned long long* Hx = (unsigned long long*)(ws + 1310720); // 256 KB
        int*      flags = (int*)(ws + 1572864);       // 2 KB
        _Float16* Hbuf  = (_Float16*)(ws + 2097152);  // 128 MB

        hipLaunchKernelGGL(setup_all, dim3(1217), dim3(64), 0, stream,
                           eWih, eWhh, ebih, ebhh, dWih, dWhh, dbih, dbhh, Wd, bd,
                           W16E, W16D, wihP, wdP, biasEP, biasDP, flags);

        hipLaunchKernelGGL(lstm_split, dim3(32), dim3(512), 0, stream,
                           x, W16E, W16D, wihP, biasEP, biasDP, Hx, flags, Hbuf);

        hipLaunchKernelGGL(out_proj, dim3(16384), dim3(256), 0, stream,
                           Hbuf, wdP, bd, (float*)d_out);
    } else {
        char* ws = (char*)d_ws;
        _Float16* whh16 = (_Float16*)(ws + 0);
        _Float16* wp16  = (_Float16*)(ws + 524288);
        _Float16* wih16 = (_Float16*)(ws + 1048576);
        _Float16* wd16  = (_Float16*)(ws + 1179648);
        float*    biasE = (float*)(ws + 1212416);
        float*    biasD = (float*)(ws + 1216512);
        hipLaunchKernelGGL(setup_fb, dim3(1024), dim3(256), 0, stream,
                           eWih, eWhh, ebih, ebhh, dWih, dWhh, dbih, dbhh, Wd, bd,
                           whh16, wp16, wih16, wd16, biasE, biasD);
        hipLaunchKernelGGL(lstm_fb, dim3(16), dim3(1024), 0, stream,
                           x, whh16, wp16, wih16, wd16, biasE, biasD, bd, (float*)d_out);
    }
}